// Round 5
// baseline (169.795 us; speedup 1.0000x reference)
//
#include <hip/hip_runtime.h>
#include <stdint.h>

#define DIMC 256
#define RTOT 1024
#define NE 64
#define NSLOT 1024
#define RCN 8      // r-chunks (grid.y)
#define RCW 128    // r-columns per chunk
#define TILE 32    // max slots per pass (2 MFMA m-tiles)
#define XSTR 264   // padded LDS row stride for A-operand (bf16 elems)

typedef short bfrag __attribute__((ext_vector_type(8)));
typedef float f32x4 __attribute__((ext_vector_type(4)));

#define WAITV(n) asm volatile("s_waitcnt vmcnt(" #n ")" ::: "memory")
#define LGKM0_BAR()                                          \
  do {                                                       \
    asm volatile("s_waitcnt lgkmcnt(0)" ::: "memory");       \
    __builtin_amdgcn_s_barrier();                            \
  } while (0)

static __device__ __forceinline__ unsigned short f2bf(float f) {
  unsigned u = __float_as_uint(f);  // RNE
  return (unsigned short)((u + 0x7FFFu + ((u >> 16) & 1u)) >> 16);
}

static __device__ __forceinline__ bfrag pack8(const float* f) {
  union { unsigned short u[8]; bfrag v; } r;
#pragma unroll
  for (int i = 0; i < 8; ++i) r.u[i] = f2bf(f[i]);
  return r.v;
}

static __device__ __forceinline__ void gload16(const float* g, float* l) {
  __builtin_amdgcn_global_load_lds(
      (const __attribute__((address_space(1))) void*)g,
      (__attribute__((address_space(3))) void*)l, 16, 0, 0);
}

// per-wave FIFO pacing: after issuing 16 L1 loads, tile ks is complete once
// outstanding <= 2*(7-ks). Counting is exact: vmcnt==0 at issue time (the
// preceding __syncthreads drained it) and no other VMEM ops intervene.
static __device__ __forceinline__ void waitv_l1(int ks) {
  switch (ks) {
    case 0: WAITV(14); break; case 1: WAITV(12); break;
    case 2: WAITV(10); break; case 3: WAITV(8);  break;
    case 4: WAITV(6);  break; case 5: WAITV(4);  break;
    case 6: WAITV(2);  break; default: WAITV(0); break;
  }
}
static __device__ __forceinline__ void waitv_l2(int rt) {
  switch (rt) {
    case 0: WAITV(12); break; case 1: WAITV(8); break;
    case 2: WAITV(4);  break; default: WAITV(0); break;
  }
}

// ---------------- fused bucketing + 2-layer expert MLP via MFMA -------------
// R5 restructure: the R0-R4 variants all tied at ~50-56us even with weights
// L3-resident (R4 replay: 9MB HBM, still 50us) -> the cost is the serialized
// chain (16 lockstep tile-steps x barriers), not memory service. Here each
// wave owns a PRIVATE 16KB LDS region and stages only ITS W1 columns (then
// ITS W2 columns) via global_load_lds: all 16 L1 loads issued in one burst,
// consumed with per-wave counted vmcnt (no barriers); L2's 16 loads issued
// right after, latency hidden under the h-park barriers. Chain per pass:
// ~3 round-trips + 5 barriers (vs ~16 round-trips + 18 barriers).
// LDS: 128KB wave-private + 16.5KB X -> 1 block/CU, 512 blocks = 2 rounds.
// Epilogue: R4's partial-store into ws (USE_WS=1) or atomic fallback.
// C/D: col=lane&15, row=(lane>>4)*4+reg.
template <int USE_WS>
__global__ __launch_bounds__(512, 2) void mlp_kernel(
    const float* __restrict__ slots, const float* __restrict__ w1,
    const float* __restrict__ b1, const float* __restrict__ w2,
    const float* __restrict__ b2, const int* __restrict__ indices,
    float* __restrict__ part, float* __restrict__ out) {
  const int e  = blockIdx.x;   // 0..63  (fast dim -> XCD id = e%8)
  const int rc = blockIdx.y;   // 0..7
  const int t  = threadIdx.x;
  const int l  = t & 63;       // lane
  const int w  = t >> 6;       // wave 0..7
  const int ln = l & 15;       // fragment n/m index
  const int kg = l >> 4;       // k-group 0..3
  const int rbase = rc * RCW;

  __shared__ __align__(16) float WB[8][4096];              // 128 KB, 16KB/wave
  __shared__ __align__(16) unsigned short X[TILE * XSTR];  // 16.5 KB A-operand
  __shared__ unsigned short blist[NSLOT];                  // 2 KB
  __shared__ int sid[TILE];
  __shared__ int bn_s;

  // ---- in-block bucketing ----
  if (t == 0) bn_s = 0;
  __syncthreads();
  {
    int i0 = indices[t] & (NE - 1);
    int i1 = indices[t + 512] & (NE - 1);
    if (i0 == e) { int p = atomicAdd(&bn_s, 1); blist[p] = (unsigned short)t; }
    if (i1 == e) { int p = atomicAdd(&bn_s, 1); blist[p] = (unsigned short)(t + 512); }
  }
  __syncthreads();
  const int n = bn_s;
  if (n == 0) return;

  const float* w1e = w1 + (size_t)e * DIMC * RTOT + rbase;                 // [d][r]
  const float* w2e = w2 + (size_t)e * RTOT * DIMC + (size_t)rbase * DIMC;  // [r][dout]
  const int   c    = w * 16 + ln;            // wave-local L1 column 0..127
  const float b1v  = b1[e * RTOT + rbase + c];
  float* WBw = WB[w];                        // this wave's private region
  float* prc = part + (size_t)rc * NSLOT * DIMC;

  // staging lane decompositions (linear LDS dest = base + l*16B required)
  const int r4 = l >> 2, c4 = (l & 3) * 4;   // L1: 16 rows x 16 cols / instr
  const int r8 = l >> 3, c8 = (l & 7) * 4;   // L2: 8 rows x 32 cols / instr

  for (int s0 = 0; s0 < n; s0 += TILE) {
    const int m = (n - s0 < TILE) ? (n - s0) : TILE;

    __syncthreads();  // prev pass fully done (drains epilogue stores too)
    if (t < TILE) sid[t] = (t < m) ? (int)blist[s0 + t] : 0;
    __syncthreads();

    // ---- stage x tile: fp32 global -> bf16 LDS [slot][d]; zero pad rows
#pragma unroll
    for (int i = t; i < TILE * 64; i += 512) {
      int s = i >> 6, d4 = (i & 63) * 4;
      float4 v = make_float4(0.f, 0.f, 0.f, 0.f);
      if (s < m) v = ((const float4*)slots)[(size_t)sid[s] * 64 + (i & 63)];
      union { unsigned short u[4]; uint2 q; } p;
      p.u[0] = f2bf(v.x); p.u[1] = f2bf(v.y);
      p.u[2] = f2bf(v.z); p.u[3] = f2bf(v.w);
      *(uint2*)&X[s * XSTR + d4] = p.q;
    }
    __syncthreads();  // x visible; also vmcnt==0 here (loads consumed)

    // ==== issue ALL L1 weight loads: wave's 16 cols x 256 k = 16 KB ====
    // WBw layout: [8 tiles][32 rows][16 cols] fp32
#pragma unroll
    for (int ks = 0; ks < 8; ++ks)
#pragma unroll
      for (int hf = 0; hf < 2; ++hf) {
        const float* src =
            w1e + (size_t)(ks * 32 + hf * 16 + r4) * RTOT + w * 16 + c4;
        gload16(src, WBw + ks * 512 + hf * 256 + l * 4);
      }

    // ==== layer 1 consume: per-wave pacing, NO barriers ====
    f32x4 acc1[2];
    acc1[0] = (f32x4)(0.f); acc1[1] = (f32x4)(0.f);
#pragma unroll
    for (int ks = 0; ks < 8; ++ks) {
      waitv_l1(ks);
      float f[8];
#pragma unroll
      for (int j = 0; j < 8; ++j) f[j] = WBw[ks * 512 + (kg * 8 + j) * 16 + ln];
      bfrag b = pack8(f);
      bfrag a0 = *(const bfrag*)&X[ln * XSTR + ks * 32 + kg * 8];
      bfrag a1 = *(const bfrag*)&X[(16 + ln) * XSTR + ks * 32 + kg * 8];
      acc1[0] = __builtin_amdgcn_mfma_f32_16x16x32_bf16(a0, b, acc1[0], 0, 0, 0);
      acc1[1] = __builtin_amdgcn_mfma_f32_16x16x32_bf16(a1, b, acc1[1], 0, 0, 0);
    }

    // ==== issue ALL L2 weight loads into the SAME private region ====
    // guard: all L1 ds_reads retired before overwriting (they are, via use)
    asm volatile("s_waitcnt lgkmcnt(0)" ::: "memory");
    // WBw layout: [4 rt][32 rows][32 cols] fp32; latency hides under h-park
#pragma unroll
    for (int rt = 0; rt < 4; ++rt)
#pragma unroll
      for (int q = 0; q < 4; ++q) {
        const float* src =
            w2e + (size_t)(rt * 32 + q * 8 + r8) * DIMC + w * 32 + c8;
        gload16(src, WBw + rt * 1024 + q * 256 + l * 4);
      }

    LGKM0_BAR();  // all waves done reading x from X (vmcnt NOT drained)

    // ---- bias + relu, park h (bf16) into X[slot][r_local]
#pragma unroll
    for (int mt = 0; mt < 2; ++mt)
#pragma unroll
      for (int reg = 0; reg < 4; ++reg) {
        float h = fmaxf(acc1[mt][reg] + b1v, 0.f);
        X[(mt * 16 + kg * 4 + reg) * XSTR + c] = f2bf(h);
      }
    LGKM0_BAR();  // parked h visible

    // ==== layer 2 consume: per-wave pacing ====
    f32x4 acc2[2][2];
#pragma unroll
    for (int mt = 0; mt < 2; ++mt)
#pragma unroll
      for (int nt = 0; nt < 2; ++nt) acc2[mt][nt] = (f32x4)(0.f);
#pragma unroll
    for (int rt = 0; rt < 4; ++rt) {
      waitv_l2(rt);
      bfrag a0 = *(const bfrag*)&X[ln * XSTR + rt * 32 + kg * 8];
      bfrag a1 = *(const bfrag*)&X[(16 + ln) * XSTR + rt * 32 + kg * 8];
#pragma unroll
      for (int nt = 0; nt < 2; ++nt) {
        float f[8];
#pragma unroll
        for (int j = 0; j < 8; ++j)
          f[j] = WBw[rt * 1024 + (kg * 8 + j) * 32 + nt * 16 + ln];
        bfrag b = pack8(f);
        acc2[0][nt] = __builtin_amdgcn_mfma_f32_16x16x32_bf16(a0, b, acc2[0][nt], 0, 0, 0);
        acc2[1][nt] = __builtin_amdgcn_mfma_f32_16x16x32_bf16(a1, b, acc2[1][nt], 0, 0, 0);
      }
    }

    // ---- epilogue: wave owns out cols w*32 + nt*16 + ln
#pragma unroll
    for (int nt = 0; nt < 2; ++nt) {
      const int col = w * 32 + nt * 16 + ln;
      const float b2v = (!USE_WS && rc == 0) ? b2[e * DIMC + col] : 0.f;
#pragma unroll
      for (int mt = 0; mt < 2; ++mt)
#pragma unroll
        for (int reg = 0; reg < 4; ++reg) {
          const int row = mt * 16 + kg * 4 + reg;
          if (row < m) {
            if (USE_WS) {
              prc[(size_t)sid[row] * DIMC + col] = acc2[mt][nt][reg];
            } else {
              atomicAdd(&out[(size_t)sid[row] * DIMC + col],
                        acc2[mt][nt][reg] + b2v);
            }
          }
        }
    }
  }
}

// ---------------- reduce: out[slot][c] = sum_rc part[rc][slot][c] + b2 ------
__global__ __launch_bounds__(256) void reduce_kernel(
    const float* __restrict__ part, const float* __restrict__ b2,
    const int* __restrict__ indices, float* __restrict__ out) {
  const int i = blockIdx.x * 256 + threadIdx.x;  // 0..65535 float4s
  const int slot = i >> 6;
  const int e = indices[slot] & (NE - 1);
  f32x4 s = *(const f32x4*)(b2 + e * DIMC + (i & 63) * 4);
#pragma unroll
  for (int rc = 0; rc < RCN; ++rc)
    s += *(const f32x4*)(part + (size_t)rc * NSLOT * DIMC + (size_t)i * 4);
  *(f32x4*)(out + (size_t)i * 4) = s;
}

extern "C" void kernel_launch(void* const* d_in, const int* in_sizes, int n_in,
                              void* d_out, int out_size, void* d_ws, size_t ws_size,
                              hipStream_t stream) {
  const float* slots   = (const float*)d_in[0];
  const float* w1      = (const float*)d_in[1];
  const float* b1      = (const float*)d_in[2];
  const float* w2      = (const float*)d_in[3];
  const float* b2      = (const float*)d_in[4];
  const int*   indices = (const int*)d_in[5];
  float* out = (float*)d_out;

  const size_t need = (size_t)RCN * NSLOT * DIMC * sizeof(float);  // 8 MB
  if (ws_size >= need) {
    float* part = (float*)d_ws;
    mlp_kernel<1><<<dim3(NE, RCN), 512, 0, stream>>>(slots, w1, b1, w2, b2,
                                                     indices, part, out);
    reduce_kernel<<<NSLOT * DIMC / 4 / 256, 256, 0, stream>>>(part, b2,
                                                              indices, out);
  } else {
    hipMemsetAsync(d_out, 0, (size_t)out_size * sizeof(float), stream);
    mlp_kernel<0><<<dim3(NE, RCN), 512, 0, stream>>>(slots, w1, b1, w2, b2,
                                                     indices, nullptr, out);
  }
}